// Round 2
// baseline (429.659 us; speedup 1.0000x reference)
//
#include <hip/hip_runtime.h>

// BagRE: segment-mean over sorted bags + linear classifier, fused.
//   hidden [N=262144, H=256] f32, W [C=128, H=256] f32, b [C] f32,
//   bag_id [N] i32 (sorted)  ->  out [NUM_BAGS=8192, C=128] f32
//
// R2 theory: kernel ~70us vs ~43us traffic floor. Occupancy is NOT the
// limiter (R1: 2x waves = neutral; MLP margin is 14x). Invariant costs:
//   (a) synchronized startup bubble: 18-deep dependent-load binary search
//       on every wave before any hidden byte is requested (~2-7us, HBM idle)
//   (b) static per-CU Poisson load imbalance (~+6-9% makespan tail)
//   (c) phase-2 lock-step serialization within blocks
// Fixes: dynamic chunk-stealing via global ticket (balances CUs, desyncs
// bubbles so they hide under other blocks' streaming), and a 3-round
// parallel wide search (262144 = 64^3: one load+ballot per round) instead
// of 18 dependent probes. Phase-2: 2 bags/thread full-K dot, no s_part.

#define NBAGS 8192
#define HDIM 256
#define CDIM 128
#define BPB 4                   // bags per chunk == waves per block
#define NCHUNK (NBAGS / BPB)    // 2048 work units, 1024 blocks -> stealing slack

// lower_bound(target) over sorted bag_id[0..N), N = 262144 = 64^3.
// 3 rounds, each: 64 lanes probe in parallel, one load + ballot.
// Invariant after each round: lb in [base, base + width], bag_id[base] < T
// or base == 0. All 64 lanes compute identical result (no shfl needed).
__device__ __forceinline__ int wide_lb(const int* __restrict__ bag_id,
                                       int target, int lane)
{
    int v = bag_id[lane << 12];                         // stride 4096
    int c = __popcll(__ballot(v < target));
    int base = (c > 0 ? c - 1 : 0) << 12;

    v = bag_id[base + (lane << 6)];                     // stride 64
    c = __popcll(__ballot(v < target));
    base += (c > 0 ? c - 1 : 0) << 6;

    v = bag_id[base + lane];                            // stride 1
    c = __popcll(__ballot(v < target));
    return base + c;                                    // == lower_bound
}

__global__ __launch_bounds__(256) void bagre_kernel(
    const float* __restrict__ hidden,
    const float* __restrict__ W,
    const float* __restrict__ b,
    const int* __restrict__ bag_id,
    float* __restrict__ out,
    int* __restrict__ ticket,
    int N)
{
    __shared__ __align__(16) float s_mean[BPB][HDIM];   // 4 KB
    __shared__ int s_tk;

    const int t    = threadIdx.x;
    const int wid  = t >> 6;        // wave id == bag index within chunk
    const int lane = t & 63;
    const int col4 = lane << 2;

    for (;;) {
        if (t == 0) s_tk = atomicAdd(ticket, 1);
        __syncthreads();                            // B1: ticket visible;
        const int tk = s_tk;                        // also fences s_mean reuse
        if (tk >= NCHUNK) break;
        const int g0 = tk * BPB;

        // --- per-wave bounds via parallel wide search (~6 L2-hot loads) ---
        const int g = g0 + wid;
        const int s = wide_lb(bag_id, g, lane);
        const int e = wide_lb(bag_id, g + 1, lane);

        // --- phase 1: wave streams its bag; lane holds 4 consecutive cols
        // (64 lanes x float4 = full 1 KB row -> one wave transaction/row) ---
        float4 a0 = make_float4(0.f, 0.f, 0.f, 0.f);
        float4 a1 = a0, a2 = a0, a3 = a0;

        const float* __restrict__ p = hidden + (size_t)s * HDIM + col4;
        int r = s;
        for (; r + 4 <= e; r += 4, p += 4 * HDIM) {
            const float4 v0 = *(const float4*)(p + 0 * HDIM);
            const float4 v1 = *(const float4*)(p + 1 * HDIM);
            const float4 v2 = *(const float4*)(p + 2 * HDIM);
            const float4 v3 = *(const float4*)(p + 3 * HDIM);
            a0.x += v0.x; a0.y += v0.y; a0.z += v0.z; a0.w += v0.w;
            a1.x += v1.x; a1.y += v1.y; a1.z += v1.z; a1.w += v1.w;
            a2.x += v2.x; a2.y += v2.y; a2.z += v2.z; a2.w += v2.w;
            a3.x += v3.x; a3.y += v3.y; a3.z += v3.z; a3.w += v3.w;
        }
        for (; r < e; ++r, p += HDIM) {
            const float4 v0 = *(const float4*)p;
            a0.x += v0.x; a0.y += v0.y; a0.z += v0.z; a0.w += v0.w;
        }

        const int cnt = e - s;
        const float inv = 1.0f / (float)(cnt > 1 ? cnt : 1);
        float4 m;
        m.x = (a0.x + a1.x + a2.x + a3.x) * inv;
        m.y = (a0.y + a1.y + a2.y + a3.y) * inv;
        m.z = (a0.z + a1.z + a2.z + a3.z) * inv;
        m.w = (a0.w + a1.w + a2.w + a3.w) * inv;
        *(float4*)(&s_mean[wid][col4]) = m;

        __syncthreads();                            // B2: means ready

        // --- phase 2: logits = mean @ W^T + b. Thread t: class c = t&127,
        // bags {jb, jb+1} with jb = (t>>7)*2 (wave-uniform -> s_mean reads
        // are LDS broadcasts). Full-K dot per bag -> no s_part, no barrier.
        {
            const int c  = t & (CDIM - 1);
            const int jb = (t >> 7) << 1;
            const float* __restrict__ wrow = W + (size_t)c * HDIM;
            float acc0 = 0.f, acc1 = 0.f;
#pragma unroll 8
            for (int k = 0; k < HDIM; k += 4) {
                const float4 wv = *(const float4*)(wrow + k);
                const float4 m0 = *(const float4*)(&s_mean[jb][k]);
                const float4 m1 = *(const float4*)(&s_mean[jb + 1][k]);
                acc0 += m0.x * wv.x + m0.y * wv.y + m0.z * wv.z + m0.w * wv.w;
                acc1 += m1.x * wv.x + m1.y * wv.y + m1.z * wv.z + m1.w * wv.w;
            }
            const float bc = b[c];
            out[(size_t)(g0 + jb)     * CDIM + c] = acc0 + bc;
            out[(size_t)(g0 + jb + 1) * CDIM + c] = acc1 + bc;
        }
        // loop: next B1 fences s_mean overwrite against this GEMV's reads
    }
}

extern "C" void kernel_launch(void* const* d_in, const int* in_sizes, int n_in,
                              void* d_out, int out_size, void* d_ws, size_t ws_size,
                              hipStream_t stream) {
    const float* hidden = (const float*)d_in[0];
    const float* W      = (const float*)d_in[1];
    const float* b      = (const float*)d_in[2];
    const int*   bag_id = (const int*)d_in[3];
    float* out = (float*)d_out;
    const int N = in_sizes[3];  // 262144

    // ticket counter lives in workspace; stream-ordered init (graph-capturable)
    hipMemsetAsync(d_ws, 0, sizeof(int), stream);
    bagre_kernel<<<1024, 256, 0, stream>>>(hidden, W, b, bag_id, out,
                                           (int*)d_ws, N);
}

// Round 5
// 354.732 us; speedup vs baseline: 1.2112x; 1.2112x over previous
//
#include <hip/hip_runtime.h>

// BagRE: segment-mean over sorted bags + linear classifier, fused.
//   hidden [N=262144, H=256] f32, W [C=128, H=256] f32, b [C] f32,
//   bag_id [N] i32 (sorted)  ->  out [NUM_BAGS=8192, C=128] f32
//
// R5 = R3 with the nontemporal-builtin type fixed (clang ext_vector_type
// instead of HIP_vector_type -- the builtin rejects the latter).
// Structure = R0 (measured best: 387.8us; static 8 bags/block, 1024
// blocks, 2 bags/wave, one phase-1 barrier) + two targeted fixes:
//  (1) startup bubble: R0 spent ~4-5us in an 18-deep DEPENDENT-load
//      binary search on 9 threads while 3 waves waited at a barrier,
//      chip-wide. Now each wave resolves its own 3 bounds via a 3-round
//      wave-parallel search (N = 262144 = 64^3: one load+ballot/round,
//      correctness proven in R2) and streams IMMEDIATELY -- no barrier
//      before phase 1 at all.
//  (2) hidden is stream-once (harness fills evict L3 between iterations):
//      nontemporal loads/stores keep W + bag_id resident in L1/L2.
// R1 lesson: occupancy is not the limiter (2x waves = neutral).
// R2 lesson: dynamic ticket stealing = -40us (serialized atomic+search).

#define NBAGS 8192
#define HDIM 256
#define CDIM 128
#define BPB 8  // bags per block (2 per wave)

typedef float f4 __attribute__((ext_vector_type(4)));

__device__ __forceinline__ f4 ntload(const float* __restrict__ p) {
    return __builtin_nontemporal_load((const f4*)p);
}

// lower_bound(target) over sorted bag_id[0..262144), 262144 = 64^3.
// 3 rounds; each: 64 lanes probe in parallel, one load + ballot + popcount.
// All lanes return the identical result (wave-uniform, no shfl needed).
// Full wave must be active (ballot).
__device__ __forceinline__ int wide_lb(const int* __restrict__ bag_id,
                                       int target, int lane)
{
    int v = bag_id[lane << 12];                         // stride 4096
    int c = __popcll(__ballot(v < target));
    int base = (c > 0 ? c - 1 : 0) << 12;

    v = bag_id[base + (lane << 6)];                     // stride 64
    c = __popcll(__ballot(v < target));
    base += (c > 0 ? c - 1 : 0) << 6;

    v = bag_id[base + lane];                            // stride 1
    c = __popcll(__ballot(v < target));
    return base + c;                                    // == lower_bound
}

__global__ __launch_bounds__(256) void bagre_kernel(
    const float* __restrict__ hidden,
    const float* __restrict__ W,
    const float* __restrict__ b,
    const int* __restrict__ bag_id,
    float* __restrict__ out,
    int N)
{
    __shared__ __align__(16) float s_mean[BPB][HDIM];   // 8 KB
    __shared__ float s_part[2][BPB][CDIM];              // 8 KB

    const int t  = threadIdx.x;
    const int g0 = blockIdx.x * BPB;

    const int q    = t >> 6;    // wave id; owns bags 2q, 2q+1
    const int lane = t & 63;
    const int col4 = lane << 2;

    // --- per-wave bounds: 3 wide searches, ~9 scattered loads total,
    // no LDS, no barrier -- this wave starts streaming the moment its
    // own bounds resolve. ---
    const int b0 = wide_lb(bag_id, g0 + 2 * q,     lane);
    const int b1 = wide_lb(bag_id, g0 + 2 * q + 1, lane);
    const int b2 = wide_lb(bag_id, g0 + 2 * q + 2, lane);

    // --- phase 1: wave streams its 2 bags; lane holds 4 consecutive cols
    // (64 lanes x 16B = full 1 KB row = one contiguous wave transaction).
#pragma unroll
    for (int jj = 0; jj < 2; ++jj) {
        const int j = q * 2 + jj;
        const int s = jj ? b1 : b0;
        const int e = jj ? b2 : b1;

        f4 a0 = (f4)0.0f, a1 = (f4)0.0f, a2 = (f4)0.0f, a3 = (f4)0.0f;

        const float* __restrict__ p = hidden + (size_t)s * HDIM + col4;
        int r = s;
        for (; r + 4 <= e; r += 4, p += 4 * HDIM) {
            // 4 independent nt 16 B loads -> 4 KB/wave in flight
            a0 += ntload(p + 0 * HDIM);
            a1 += ntload(p + 1 * HDIM);
            a2 += ntload(p + 2 * HDIM);
            a3 += ntload(p + 3 * HDIM);
        }
        for (; r < e; ++r, p += HDIM) {
            a0 += ntload(p);
        }

        const int cnt = e - s;
        const float inv = 1.0f / (float)(cnt > 1 ? cnt : 1);
        const f4 m = (a0 + a1 + a2 + a3) * inv;
        *(f4*)(&s_mean[j][col4]) = m;
    }
    __syncthreads();  // the ONLY pre-phase-2 barrier

    // --- phase 2: logits = mean @ W^T + b, 8-bag register blocking ---
    // thread t: class c = t&127, K-half = t>>7. W value reused across 8 bags.
    // hbase is wave-uniform -> s_mean reads are LDS broadcasts (free).
    const int c    = t & (CDIM - 1);
    const int half = t >> 7;
    const float* __restrict__ wrow = W + (size_t)c * HDIM + half * (HDIM / 2);

    float acc[BPB];
#pragma unroll
    for (int j = 0; j < BPB; ++j) acc[j] = 0.f;

    for (int hh = 0; hh < HDIM / 2; hh += 4) {
        const f4 wv = *(const f4*)(wrow + hh);
        const int hbase = half * (HDIM / 2) + hh;
#pragma unroll
        for (int j = 0; j < BPB; ++j) {
            acc[j] += s_mean[j][hbase + 0] * wv.x
                    + s_mean[j][hbase + 1] * wv.y
                    + s_mean[j][hbase + 2] * wv.z
                    + s_mean[j][hbase + 3] * wv.w;
        }
    }

#pragma unroll
    for (int j = 0; j < BPB; ++j) s_part[half][j][c] = acc[j];
    __syncthreads();

    for (int idx = t; idx < BPB * CDIM; idx += 256) {
        const int j  = idx >> 7;
        const int cc = idx & (CDIM - 1);
        const float v = s_part[0][j][cc] + s_part[1][j][cc] + b[cc];
        __builtin_nontemporal_store(v, &out[(size_t)(g0 + j) * CDIM + cc]);
    }
}

extern "C" void kernel_launch(void* const* d_in, const int* in_sizes, int n_in,
                              void* d_out, int out_size, void* d_ws, size_t ws_size,
                              hipStream_t stream) {
    const float* hidden = (const float*)d_in[0];
    const float* W      = (const float*)d_in[1];
    const float* b      = (const float*)d_in[2];
    const int*   bag_id = (const int*)d_in[3];
    float* out = (float*)d_out;
    const int N = in_sizes[3];  // 262144

    bagre_kernel<<<NBAGS / BPB, 256, 0, stream>>>(hidden, W, b, bag_id, out, N);
}